// Round 7
// baseline (254.972 us; speedup 1.0000x reference)
//
#include <hip/hip_runtime.h>

#define N_EDGES 800000
#define N_NODES 50000
#define D 64                 // D_FEAT == EDGE_DIM == 64
#define NPB 196              // node_proj blocks per table (196*256 >= 50000 rows)

typedef __attribute__((ext_vector_type(8))) short    bf16x8;  // 8 bf16 = 16 B
typedef __attribute__((ext_vector_type(4))) float    f32x4;
typedef __attribute__((ext_vector_type(4))) _Float16 f16x4;   // 8 B

#if __has_builtin(__builtin_amdgcn_exp2f)
#define EXP2F(x) __builtin_amdgcn_exp2f(x)
#else
#define EXP2F(x) __expf(0.69314718055994531f * (x))
#endif

// f32 -> bf16 round-to-nearest-even (finite inputs)
__device__ __forceinline__ unsigned short f2bf(float f) {
    unsigned int u = __float_as_uint(f);
    u += 0x7fffu + ((u >> 16) & 1u);
    return (unsigned short)(u >> 16);
}
__device__ __forceinline__ unsigned int pack2(float a, float b) {
    return (unsigned int)f2bf(a) | ((unsigned int)f2bf(b) << 16);
}

// Per-node projection into f16 tables:
//   Pr = nf @ W[0:64] + bias   (bias folded here, once per node)
//   Ps = nf @ W[64:128]
// One table per block (tab = blockIdx.x >= NPB). Each block builds its tab's W
// fragment half (8 KB) in LDS from W directly (L2-hot after block 0).
// Fragment order (verified r0-r5): idx=(ki2*4+nt)*64+l, l=q*16+m:
//   frag[j] = bf16(W[(tab*2+ki2)*32 + q*8 + j][nt*16+m])
// Operand-swapped MFMA: acc[mt][nt][r] = P[node=n0+mt*16+m][feat=nt*16+q*4+r]
__global__ __launch_bounds__(256) void node_proj(
    const float* __restrict__ nf, const float* __restrict__ W,
    const float* __restrict__ bias,
    _Float16* __restrict__ Pr, _Float16* __restrict__ Ps)
{
    __shared__ bf16x8 lds_b[512];                 // 8 KB: this tab's half of W

    const int tab = blockIdx.x >= NPB;            // 0: recv -> Pr, 1: send -> Ps
    const int bid = tab ? blockIdx.x - NPB : blockIdx.x;

#pragma unroll
    for (int i = 0; i < 2; ++i) {
        const int idx = i * 256 + threadIdx.x;    // 0..511
        const int ki2 = idx >> 8;
        const int nt  = (idx >> 6) & 3;
        const int l   = idx & 63;
        const int mm  = l & 15, qq = l >> 4;
        const int kbase = (tab * 2 + ki2) * 32 + qq * 8;
        const int n = nt * 16 + mm;
        union { bf16x8 v; unsigned short h[8]; } cv;
#pragma unroll
        for (int j = 0; j < 8; ++j)
            cv.h[j] = f2bf(W[(kbase + j) * D + n]);
        lds_b[idx] = cv.v;
    }
    __syncthreads();

    const int lane = threadIdx.x & 63;
    const int m    = lane & 15;
    const int q    = lane >> 4;
    const int wid  = bid * 4 + (threadIdx.x >> 6);
    const int n0   = wid * 64;

    // A fragments from contiguous f32 node rows -> bf16; k = ki2*32 + q*8 + j
    bf16x8 a[2][4];
#pragma unroll
    for (int mt = 0; mt < 4; ++mt) {
        const int row = n0 + mt * 16 + m;
        const int rl  = row < N_NODES ? row : N_NODES - 1;   // clamp tail loads
        const float* rp = nf + (long)rl * D;
#pragma unroll
        for (int kk = 0; kk < 2; ++kk) {
            const float4 lo = *(const float4*)(rp + kk * 32 + q * 8);
            const float4 hi = *(const float4*)(rp + kk * 32 + q * 8 + 4);
            union { bf16x8 v; unsigned int u[4]; } cv;
            cv.u[0] = pack2(lo.x, lo.y);
            cv.u[1] = pack2(lo.z, lo.w);
            cv.u[2] = pack2(hi.x, hi.y);
            cv.u[3] = pack2(hi.z, hi.w);
            a[kk][mt] = cv.v;
        }
    }

    f32x4 acc[4][4];
#pragma unroll
    for (int mt = 0; mt < 4; ++mt)
#pragma unroll
        for (int nt = 0; nt < 4; ++nt)
            acc[mt][nt] = (f32x4)0.0f;

#pragma unroll
    for (int ki2 = 0; ki2 < 2; ++ki2) {
#pragma unroll
        for (int nt = 0; nt < 4; ++nt) {
            const bf16x8 bf = lds_b[(ki2 * 4 + nt) * 64 + lane];
#pragma unroll
            for (int mt = 0; mt < 4; ++mt)
                acc[mt][nt] = __builtin_amdgcn_mfma_f32_16x16x32_bf16(
                    bf, a[ki2][mt], acc[mt][nt], 0, 0, 0);
        }
    }

    // Bias fold (recv table only), f32 -> f16, store 8 B per (mt,nt).
    f32x4 bv[4];
#pragma unroll
    for (int nt = 0; nt < 4; ++nt) {
        const float4 b4 = *(const float4*)(bias + nt * 16 + q * 4);
        bv[nt] = tab ? (f32x4)0.0f : (f32x4){b4.x, b4.y, b4.z, b4.w};
    }

    _Float16* __restrict__ P = tab ? Ps : Pr;
#pragma unroll
    for (int mt = 0; mt < 4; ++mt) {
        const int row = n0 + mt * 16 + m;
        if (row < N_NODES) {
            _Float16* op = P + (long)row * D + q * 4;
#pragma unroll
            for (int nt = 0; nt < 4; ++nt) {
                const f32x4 v = acc[mt][nt] + bv[nt];
                const f16x4 h = {(_Float16)v[0], (_Float16)v[1],
                                 (_Float16)v[2], (_Float16)v[3]};
                *(f16x4*)(op + nt * 16) = h;
            }
        }
    }
}

// Streaming edge kernel: out[e] = tanh(Pr[recv[e]] + Ps[send[e]])  (bias in Pr).
// Wave = 32 edges in TWO 16-edge batches (identical per-batch mapping to r5,
// which proved full-line-per-instruction NT stores / packed gathers):
//   lane l: sub = l>>4, fs = (l&15)*4; batch b handles edges
//   eb + b*16 + sub*4 + g (g=0..3), feature slice [fs, fs+4).
// ALL 16 gathers (both batches) are issued before any use -> 128 B/lane in
// flight (2x r5) to hide L2/L3 gather latency; batch-0 compute+store overlaps
// batch-1's outstanding loads (compiler emits partial vmcnt for batch 0).
//   gathers: 16 x f16x4 (8 B); per instr 16 lanes cover one P-row's 128 B
//            contiguously, 4 rows/instr
//   stores : 8 x NT f32x4; per instr 4 chunks x 256 B -> FULL 64 B lines
//            (r4 lesson: NT only merges within one instruction)
// ~65 VGPR, no LDS, no barriers.
__global__ __launch_bounds__(256) void edge_act(
    const _Float16* __restrict__ Pr, const _Float16* __restrict__ Ps,
    const int*   __restrict__ senders, const int* __restrict__ receivers,
    float* __restrict__ out)
{
    const int wid  = (blockIdx.x * 256 + threadIdx.x) >> 6;   // global wave id
    const int lane = threadIdx.x & 63;
    const int sub  = lane >> 4;          // 0..3
    const int fs   = (lane & 15) * 4;    // feature slice start
    const int eb   = wid * 32;           // this wave's 32 edges

    // Per-batch edge base for this lane: eb + b*16 + sub*4
    const int e0 = eb + sub * 4;
    const int e1 = e0 + 16;

    const int4 rv0 = *(const int4*)(receivers + e0);
    const int4 sv0 = *(const int4*)(senders   + e0);
    const int4 rv1 = *(const int4*)(receivers + e1);
    const int4 sv1 = *(const int4*)(senders   + e1);
    const int r0[4] = {rv0.x, rv0.y, rv0.z, rv0.w};
    const int s0[4] = {sv0.x, sv0.y, sv0.z, sv0.w};
    const int r1[4] = {rv1.x, rv1.y, rv1.z, rv1.w};
    const int s1[4] = {sv1.x, sv1.y, sv1.z, sv1.w};

    // Issue ALL 16 independent 8 B gathers before any use (128 B/lane MLP).
    f16x4 pa0[4], pb0[4], pa1[4], pb1[4];
#pragma unroll
    for (int g = 0; g < 4; ++g) {
        pa0[g] = *(const f16x4*)(Pr + (long)r0[g] * D + fs);
        pb0[g] = *(const f16x4*)(Ps + (long)s0[g] * D + fs);
    }
#pragma unroll
    for (int g = 0; g < 4; ++g) {
        pa1[g] = *(const f16x4*)(Pr + (long)r1[g] * D + fs);
        pb1[g] = *(const f16x4*)(Ps + (long)s1[g] * D + fs);
    }

    const float C2L = 2.8853900817779268f;         // 2*log2(e)

    // Batch 0: compute + store while batch-1 loads are still in flight.
#pragma unroll
    for (int g = 0; g < 4; ++g) {
        f32x4 y;
#pragma unroll
        for (int k = 0; k < 4; ++k) {
            const float x  = (float)pa0[g][k] + (float)pb0[g][k];
            const float tt = EXP2F(x * C2L);
            const float rc = __builtin_amdgcn_rcpf(tt + 1.0f);
            y[k] = __builtin_fmaf(-2.0f, rc, 1.0f);     // tanh, saturates to +/-1
        }
        __builtin_nontemporal_store(y, (f32x4*)(out + (long)(e0 + g) * D + fs));
    }

    // Batch 1.
#pragma unroll
    for (int g = 0; g < 4; ++g) {
        f32x4 y;
#pragma unroll
        for (int k = 0; k < 4; ++k) {
            const float x  = (float)pa1[g][k] + (float)pb1[g][k];
            const float tt = EXP2F(x * C2L);
            const float rc = __builtin_amdgcn_rcpf(tt + 1.0f);
            y[k] = __builtin_fmaf(-2.0f, rc, 1.0f);
        }
        __builtin_nontemporal_store(y, (f32x4*)(out + (long)(e1 + g) * D + fs));
    }
}

extern "C" void kernel_launch(void* const* d_in, const int* in_sizes, int n_in,
                              void* d_out, int out_size, void* d_ws, size_t ws_size,
                              hipStream_t stream) {
    const float* node_feats = (const float*)d_in[0];
    const int*   senders    = (const int*)d_in[1];
    const int*   receivers  = (const int*)d_in[2];
    const float* W          = (const float*)d_in[3];
    const float* bias       = (const float*)d_in[4];
    float*       out        = (float*)d_out;

    // ws layout: Pr [50000][64] f16 (6.4 MB) | Ps same
    _Float16* Pr = (_Float16*)d_ws;
    _Float16* Ps = Pr + (size_t)N_NODES * D;

    node_proj<<<2 * NPB, 256, 0, stream>>>(node_feats, W, bias, Pr, Ps);

    const int ea_blocks = (N_EDGES / 32) * 64 / 256;   // 6250 exact
    edge_act<<<ea_blocks, 256, 0, stream>>>(Pr, Ps, senders, receivers, out);
}

// Round 8
// 250.607 us; speedup vs baseline: 1.0174x; 1.0174x over previous
//
#include <hip/hip_runtime.h>

#define N_EDGES 800000
#define N_NODES 50000
#define D 64                 // D_FEAT == EDGE_DIM == 64
#define NPB 196              // node_proj blocks per table (196*256 >= 50000 rows)

typedef __attribute__((ext_vector_type(8))) short    bf16x8;  // 8 bf16 = 16 B
typedef __attribute__((ext_vector_type(4))) float    f32x4;
typedef __attribute__((ext_vector_type(4))) _Float16 f16x4;   // 8 B

#if __has_builtin(__builtin_amdgcn_exp2f)
#define EXP2F(x) __builtin_amdgcn_exp2f(x)
#else
#define EXP2F(x) __expf(0.69314718055994531f * (x))
#endif

// f32 -> bf16 round-to-nearest-even (finite inputs)
__device__ __forceinline__ unsigned short f2bf(float f) {
    unsigned int u = __float_as_uint(f);
    u += 0x7fffu + ((u >> 16) & 1u);
    return (unsigned short)(u >> 16);
}
__device__ __forceinline__ unsigned int pack2(float a, float b) {
    return (unsigned int)f2bf(a) | ((unsigned int)f2bf(b) << 16);
}

// Per-node projection into f16 tables:
//   Pr = nf @ W[0:64] + bias   (bias folded here, once per node)
//   Ps = nf @ W[64:128]
// One table per block (tab = blockIdx.x >= NPB). Each block builds its tab's W
// fragment half (8 KB) in LDS from W directly (L2-hot after block 0).
// Fragment order (verified r0-r7): idx=(ki2*4+nt)*64+l, l=q*16+m:
//   frag[j] = bf16(W[(tab*2+ki2)*32 + q*8 + j][nt*16+m])
// Operand-swapped MFMA: acc[mt][nt][r] = P[node=n0+mt*16+m][feat=nt*16+q*4+r]
__global__ __launch_bounds__(256) void node_proj(
    const float* __restrict__ nf, const float* __restrict__ W,
    const float* __restrict__ bias,
    _Float16* __restrict__ Pr, _Float16* __restrict__ Ps)
{
    __shared__ bf16x8 lds_b[512];                 // 8 KB: this tab's half of W

    const int tab = blockIdx.x >= NPB;            // 0: recv -> Pr, 1: send -> Ps
    const int bid = tab ? blockIdx.x - NPB : blockIdx.x;

#pragma unroll
    for (int i = 0; i < 2; ++i) {
        const int idx = i * 256 + threadIdx.x;    // 0..511
        const int ki2 = idx >> 8;
        const int nt  = (idx >> 6) & 3;
        const int l   = idx & 63;
        const int mm  = l & 15, qq = l >> 4;
        const int kbase = (tab * 2 + ki2) * 32 + qq * 8;
        const int n = nt * 16 + mm;
        union { bf16x8 v; unsigned short h[8]; } cv;
#pragma unroll
        for (int j = 0; j < 8; ++j)
            cv.h[j] = f2bf(W[(kbase + j) * D + n]);
        lds_b[idx] = cv.v;
    }
    __syncthreads();

    const int lane = threadIdx.x & 63;
    const int m    = lane & 15;
    const int q    = lane >> 4;
    const int wid  = bid * 4 + (threadIdx.x >> 6);
    const int n0   = wid * 64;

    // A fragments from contiguous f32 node rows -> bf16; k = ki2*32 + q*8 + j
    bf16x8 a[2][4];
#pragma unroll
    for (int mt = 0; mt < 4; ++mt) {
        const int row = n0 + mt * 16 + m;
        const int rl  = row < N_NODES ? row : N_NODES - 1;   // clamp tail loads
        const float* rp = nf + (long)rl * D;
#pragma unroll
        for (int kk = 0; kk < 2; ++kk) {
            const float4 lo = *(const float4*)(rp + kk * 32 + q * 8);
            const float4 hi = *(const float4*)(rp + kk * 32 + q * 8 + 4);
            union { bf16x8 v; unsigned int u[4]; } cv;
            cv.u[0] = pack2(lo.x, lo.y);
            cv.u[1] = pack2(lo.z, lo.w);
            cv.u[2] = pack2(hi.x, hi.y);
            cv.u[3] = pack2(hi.z, hi.w);
            a[kk][mt] = cv.v;
        }
    }

    f32x4 acc[4][4];
#pragma unroll
    for (int mt = 0; mt < 4; ++mt)
#pragma unroll
        for (int nt = 0; nt < 4; ++nt)
            acc[mt][nt] = (f32x4)0.0f;

#pragma unroll
    for (int ki2 = 0; ki2 < 2; ++ki2) {
#pragma unroll
        for (int nt = 0; nt < 4; ++nt) {
            const bf16x8 bf = lds_b[(ki2 * 4 + nt) * 64 + lane];
#pragma unroll
            for (int mt = 0; mt < 4; ++mt)
                acc[mt][nt] = __builtin_amdgcn_mfma_f32_16x16x32_bf16(
                    bf, a[ki2][mt], acc[mt][nt], 0, 0, 0);
        }
    }

    // Bias fold (recv table only), f32 -> f16, store 8 B per (mt,nt).
    f32x4 bv[4];
#pragma unroll
    for (int nt = 0; nt < 4; ++nt) {
        const float4 b4 = *(const float4*)(bias + nt * 16 + q * 4);
        bv[nt] = tab ? (f32x4)0.0f : (f32x4){b4.x, b4.y, b4.z, b4.w};
    }

    _Float16* __restrict__ P = tab ? Ps : Pr;
#pragma unroll
    for (int mt = 0; mt < 4; ++mt) {
        const int row = n0 + mt * 16 + m;
        if (row < N_NODES) {
            _Float16* op = P + (long)row * D + q * 4;
#pragma unroll
            for (int nt = 0; nt < 4; ++nt) {
                const f32x4 v = acc[mt][nt] + bv[nt];
                const f16x4 h = {(_Float16)v[0], (_Float16)v[1],
                                 (_Float16)v[2], (_Float16)v[3]};
                *(f16x4*)(op + nt * 16) = h;
            }
        }
    }
}

// Streaming edge kernel: out[e] = tanh(Pr[recv[e]] + Ps[send[e]])  (bias in Pr).
// Wave = 16 edges (the measured-best r5 mapping):
//   lane l: sub = l>>4, fs = (l&15)*4; handles edges e0 = wid*16 + sub*4 + g
//   (g=0..3), feature slice [fs, fs+4).
// VMEM-path budget (the binding resource, ~10 B/cyc/CU):
//   gathers: 8 x f16x4 (8 B/lane)  = 4 KB/wave, unique, 4x128 B segs/instr
//   stores : 4 x NT f32x4 (16 B/ln)= 4 KB/wave, unique, full 64 B lines
//   indices: ONE dword per lane    = 0.25 KB/wave (was 2 KB: r5 loaded each
//            int4 redundantly in 16 lanes; 20% of all VMEM-path bytes).
//            Lanes 0-15 load receivers[e0w+li], 16-31 senders[e0w+li],
//            32-63 mirror; distribution via 8 __shfl (DS pipe, off VMEM path).
// ~45 VGPR, no LDS, no barriers -> 8 waves/SIMD.
__global__ __launch_bounds__(256) void edge_act(
    const _Float16* __restrict__ Pr, const _Float16* __restrict__ Ps,
    const int*   __restrict__ senders, const int* __restrict__ receivers,
    float* __restrict__ out)
{
    const int wid  = (blockIdx.x * 256 + threadIdx.x) >> 6;   // global wave id
    const int lane = threadIdx.x & 63;
    const int sub  = lane >> 4;          // 0..3
    const int fs   = (lane & 15) * 4;    // feature slice start
    const int e0w  = wid * 16;           // wave's 16 edges

    // Non-redundant index load: one dword per lane, shuffled to consumers.
    const int li = lane & 15;
    const int* ip = (lane & 16) ? senders : receivers;
    const int v = ip[e0w + li];

    int r[4], s[4];
#pragma unroll
    for (int g = 0; g < 4; ++g) {
        r[g] = __shfl(v, sub * 4 + g, 64);        // from lanes 0-15 (receivers)
        s[g] = __shfl(v, 16 + sub * 4 + g, 64);   // from lanes 16-31 (senders)
    }

    // 8 independent 8 B gathers, all in flight before the first use.
    f16x4 pa[4], pb[4];
#pragma unroll
    for (int g = 0; g < 4; ++g) {
        pa[g] = *(const f16x4*)(Pr + (long)r[g] * D + fs);
        pb[g] = *(const f16x4*)(Ps + (long)s[g] * D + fs);
    }

    const float C2L = 2.8853900817779268f;         // 2*log2(e)
#pragma unroll
    for (int g = 0; g < 4; ++g) {
        f32x4 y;
#pragma unroll
        for (int k = 0; k < 4; ++k) {
            const float x  = (float)pa[g][k] + (float)pb[g][k];
            const float tt = EXP2F(x * C2L);
            const float rc = __builtin_amdgcn_rcpf(tt + 1.0f);
            y[k] = __builtin_fmaf(-2.0f, rc, 1.0f);     // tanh, saturates to +/-1
        }
        __builtin_nontemporal_store(y,
            (f32x4*)(out + (long)(e0w + sub * 4 + g) * D + fs));
    }
}

extern "C" void kernel_launch(void* const* d_in, const int* in_sizes, int n_in,
                              void* d_out, int out_size, void* d_ws, size_t ws_size,
                              hipStream_t stream) {
    const float* node_feats = (const float*)d_in[0];
    const int*   senders    = (const int*)d_in[1];
    const int*   receivers  = (const int*)d_in[2];
    const float* W          = (const float*)d_in[3];
    const float* bias       = (const float*)d_in[4];
    float*       out        = (float*)d_out;

    // ws layout: Pr [50000][64] f16 (6.4 MB) | Ps same
    _Float16* Pr = (_Float16*)d_ws;
    _Float16* Ps = Pr + (size_t)N_NODES * D;

    node_proj<<<2 * NPB, 256, 0, stream>>>(node_feats, W, bias, Pr, Ps);

    const int ea_blocks = (N_EDGES / 16) * 64 / 256;   // 12500 exact
    edge_act<<<ea_blocks, 256, 0, stream>>>(Pr, Ps, senders, receivers, out);
}